// Round 2
// baseline (620.256 us; speedup 1.0000x reference)
//
#include <hip/hip_runtime.h>

typedef __attribute__((ext_vector_type(8))) short short8;
typedef __attribute__((ext_vector_type(4))) short short4v;
typedef __attribute__((ext_vector_type(4))) float f32x4;
typedef unsigned short u16;
typedef unsigned int u32;

__device__ __forceinline__ float bf2f(u16 h) {
    return __uint_as_float(((u32)h) << 16);
}
__device__ __forceinline__ u16 f2bf(float f) {
    u32 u = __float_as_uint(f);
    u32 r = u + 0x7fffu + ((u >> 16) & 1u);   // RNE
    return (u16)(r >> 16);
}

__device__ __forceinline__ void async_copy16(const void* g, void* l) {
    __builtin_amdgcn_global_load_lds(
        (const __attribute__((address_space(1))) void*)g,
        (__attribute__((address_space(3))) void*)l, 16, 0, 0);
}

// ---------------------------------------------------------------------------
// fp32 -> (bf16 hi, bf16 lo) split conversion. lo = bf16(v - f(hi)).
// ---------------------------------------------------------------------------
__global__ __launch_bounds__(256) void cvt_split(
    const float* __restrict__ in, u16* __restrict__ hi, u16* __restrict__ lo, int n4)
{
    int i = blockIdx.x * 256 + threadIdx.x;
    if (i >= n4) return;
    float4 v = ((const float4*)in)[i];
    short4v h, l;
    float vv[4] = {v.x, v.y, v.z, v.w};
#pragma unroll
    for (int j = 0; j < 4; j++) {
        u16 hb = f2bf(vv[j]);
        h[j] = (short)hb;
        l[j] = (short)f2bf(vv[j] - bf2f(hb));
    }
    ((short4v*)hi)[i] = h;
    ((short4v*)lo)[i] = l;
}

__global__ __launch_bounds__(256) void cvt_bf(
    const float* __restrict__ in, u16* __restrict__ out, int n4)
{
    int i = blockIdx.x * 256 + threadIdx.x;
    if (i >= n4) return;
    float4 v = ((const float4*)in)[i];
    short4v h;
    h[0] = (short)f2bf(v.x); h[1] = (short)f2bf(v.y);
    h[2] = (short)f2bf(v.z); h[3] = (short)f2bf(v.w);
    ((short4v*)out)[i] = h;
}

// ---------------------------------------------------------------------------
// bf16 GEMM: C[M][N] = A[M][K] * B[N][K]^T (+C if accum). m97 structure:
// 128x128 tile, BK=32, global_load_lds width-16 staging. M,N%128==0, K%32==0.
// ---------------------------------------------------------------------------
template <typename CT>
__global__ __launch_bounds__(256) void gemm_bt(
    const u16* __restrict__ A, long lda, long bsA,
    const u16* __restrict__ Bm, long ldb, long bsB,
    CT* __restrict__ C, long ldc, long bsC, int K, int accum)
{
    __shared__ __align__(16) u16 lsA[128 * 32];
    __shared__ __align__(16) u16 lsB[128 * 32];
    const int tid = threadIdx.x;
    const int wave = tid >> 6, lane = tid & 63;
    const int quad = lane >> 4, l15 = lane & 15;
    const int wm = wave >> 1, wn = wave & 1;
    const long m0 = (long)blockIdx.x * 128, n0 = (long)blockIdx.y * 128;
    A  += (long)blockIdx.z * bsA;
    Bm += (long)blockIdx.z * bsB;
    C  += (long)blockIdx.z * bsC;
    const int srow = lane >> 2, scol = (lane & 3) * 8;

    f32x4 acc[4][4];
#pragma unroll
    for (int i = 0; i < 4; i++)
#pragma unroll
        for (int j = 0; j < 4; j++) acc[i][j] = (f32x4){0.f, 0.f, 0.f, 0.f};

    const u16* ga0 = A + (m0 + (wave * 2 + 0) * 16 + srow) * lda + scol;
    const u16* ga1 = A + (m0 + (wave * 2 + 1) * 16 + srow) * lda + scol;
    const u16* gb0 = Bm + (n0 + (wave * 2 + 0) * 16 + srow) * ldb + scol;
    const u16* gb1 = Bm + (n0 + (wave * 2 + 1) * 16 + srow) * ldb + scol;
    u16* la0 = &lsA[(wave * 2 + 0) * 512];
    u16* la1 = &lsA[(wave * 2 + 1) * 512];
    u16* lb0 = &lsB[(wave * 2 + 0) * 512];
    u16* lb1 = &lsB[(wave * 2 + 1) * 512];

    for (int kk = 0; kk < K; kk += 32) {
        async_copy16(ga0 + kk, la0);
        async_copy16(ga1 + kk, la1);
        async_copy16(gb0 + kk, lb0);
        async_copy16(gb1 + kk, lb1);
        __syncthreads();
        short8 af[4], bf[4];
#pragma unroll
        for (int mt = 0; mt < 4; mt++)
            af[mt] = *(const short8*)&lsA[(wm * 64 + mt * 16 + l15) * 32 + quad * 8];
#pragma unroll
        for (int nt = 0; nt < 4; nt++)
            bf[nt] = *(const short8*)&lsB[(wn * 64 + nt * 16 + l15) * 32 + quad * 8];
#pragma unroll
        for (int mt = 0; mt < 4; mt++)
#pragma unroll
            for (int nt = 0; nt < 4; nt++)
                acc[mt][nt] = __builtin_amdgcn_mfma_f32_16x16x32_bf16(
                    af[mt], bf[nt], acc[mt][nt], 0, 0, 0);
        __syncthreads();
    }
#pragma unroll
    for (int mt = 0; mt < 4; mt++) {
        const long rowb = m0 + wm * 64 + mt * 16 + quad * 4;
#pragma unroll
        for (int nt = 0; nt < 4; nt++) {
            const long col = n0 + wn * 64 + nt * 16 + l15;
#pragma unroll
            for (int r = 0; r < 4; r++) {
                const float v = acc[mt][nt][r];
                if constexpr (sizeof(CT) == 2) {
                    C[(rowb + r) * ldc + col] = f2bf(v);
                } else {
                    if (accum) C[(rowb + r) * ldc + col] += v;
                    else       C[(rowb + r) * ldc + col] = v;
                }
            }
        }
    }
}

// ---------------------------------------------------------------------------
// Per-token softmax over each router's 64 logits, scaled by importance,
// summed over tokens into w_raw[4][8][64] (fp32 atomics).
// One block = 32 tokens (same b). logits fp32 [8192][256]. 128 threads.
// ---------------------------------------------------------------------------
__global__ __launch_bounds__(128) void router_agg(
    const float* __restrict__ logits, const float* __restrict__ imp,
    float* __restrict__ w_raw)
{
    __shared__ float pref[32][257];
    const int tid = threadIdx.x;
    const int tl = tid >> 2, r = tid & 3;
    const int s = blockIdx.x * 32 + tl;
    const int b = s >> 10;
    const float* lp = logits + (long)s * 256 + r * 64;
    float v[64];
#pragma unroll
    for (int i = 0; i < 16; i++) {
        float4 f = ((const float4*)lp)[i];
        v[i * 4 + 0] = f.x; v[i * 4 + 1] = f.y;
        v[i * 4 + 2] = f.z; v[i * 4 + 3] = f.w;
    }
    float mx = v[0];
#pragma unroll
    for (int i = 1; i < 64; i++) mx = fmaxf(mx, v[i]);
    float sum = 0.f;
#pragma unroll
    for (int i = 0; i < 64; i++) { v[i] = __expf(v[i] - mx); sum += v[i]; }
    const float scale = imp[s] / sum;
#pragma unroll
    for (int i = 0; i < 64; i++) pref[tl][r * 64 + i] = v[i] * scale;
    __syncthreads();
#pragma unroll
    for (int half = 0; half < 2; half++) {
        const int idx = tid + half * 128;          // 0..255
        const int r2 = idx >> 6, n = idx & 63;
        float acc = 0.f;
#pragma unroll 8
        for (int t = 0; t < 32; t++) acc += pref[t][r2 * 64 + n];
        atomicAdd(&w_raw[(r2 * 8 + b) * 64 + n], acc);
    }
}

// ---------------------------------------------------------------------------
// Normalize w, top-k (k=16 router 0, else 8), renormalize.
// One 64-thread block per (router, b).
// ---------------------------------------------------------------------------
__global__ void topk_kernel(const float* __restrict__ w_raw,
                            float* __restrict__ topw, int* __restrict__ topi)
{
    const int r = blockIdx.x >> 3, b = blockIdx.x & 7;
    const int lane = threadIdx.x;
    const int k = (r == 0) ? 16 : 8;
    float w = w_raw[(r * 8 + b) * 64 + lane];
    float tot = w;
    for (int o2 = 32; o2 >= 1; o2 >>= 1) tot += __shfl_xor(tot, o2);
    w = w / (tot + 1e-8f);
    __shared__ float tw[16];
    __shared__ int ti[16];
    float cur = w;
    float ssum = 0.f;
    for (int j = 0; j < k; j++) {
        float m = cur; int mi = lane;
        for (int o2 = 32; o2 >= 1; o2 >>= 1) {
            float om = __shfl_xor(m, o2); int oi = __shfl_xor(mi, o2);
            if (om > m || (om == m && oi < mi)) { m = om; mi = oi; }
        }
        if (lane == 0) { tw[j] = m; ti[j] = mi; }
        ssum += m;
        if (lane == mi) cur = -1e30f;
    }
    __syncthreads();
    if (lane < 16) {
        topw[(r * 8 + b) * 16 + lane] = (lane < k) ? tw[lane] / (ssum + 1e-8f) : 0.f;
        topi[(r * 8 + b) * 16 + lane] = (lane < k) ? ti[lane] : 0;
    }
}

// ---------------------------------------------------------------------------
// out[b][j][i] = sum_k w[b,k] * pool[idx[b,k]][i][j]   (transposing gather-mix)
// pool: [64][I][J] fp32, out: [B][J][I] bf16. Tile 64x64, LDS transpose.
// ---------------------------------------------------------------------------
__global__ __launch_bounds__(256) void gather_mix(
    const float* __restrict__ pool, const float* __restrict__ topw,
    const int* __restrict__ topi, u16* __restrict__ out,
    int I, int J, int k)
{
    __shared__ float tile[64][65];
    const int b = blockIdx.z;
    const long IJ = (long)I * J;
    const int i0 = blockIdx.x * 64, j0 = blockIdx.y * 64;
    const float* tw = topw + b * 16;
    const int* ti = topi + b * 16;
    const int tid = threadIdx.x;
    const int il = tid >> 2, jg = tid & 3;
    float acc[16];
#pragma unroll
    for (int m = 0; m < 16; m++) acc[m] = 0.f;
    for (int kk = 0; kk < k; kk++) {
        const float wgt = tw[kk];
        const long n = ti[kk];
        const float* src = pool + n * IJ + (long)(i0 + il) * J + j0 + jg * 16;
        float4 a0 = ((const float4*)src)[0];
        float4 a1 = ((const float4*)src)[1];
        float4 a2 = ((const float4*)src)[2];
        float4 a3 = ((const float4*)src)[3];
        acc[0] += wgt * a0.x;  acc[1] += wgt * a0.y;
        acc[2] += wgt * a0.z;  acc[3] += wgt * a0.w;
        acc[4] += wgt * a1.x;  acc[5] += wgt * a1.y;
        acc[6] += wgt * a1.z;  acc[7] += wgt * a1.w;
        acc[8] += wgt * a2.x;  acc[9] += wgt * a2.y;
        acc[10] += wgt * a2.z; acc[11] += wgt * a2.w;
        acc[12] += wgt * a3.x; acc[13] += wgt * a3.y;
        acc[14] += wgt * a3.z; acc[15] += wgt * a3.w;
    }
#pragma unroll
    for (int m = 0; m < 16; m++) tile[il][jg * 16 + m] = acc[m];
    __syncthreads();
    const int jl = tid >> 2, ig = tid & 3;
    short8 o0, o1;
#pragma unroll
    for (int m = 0; m < 8; m++) {
        o0[m] = (short)f2bf(tile[ig * 16 + m][jl]);
        o1[m] = (short)f2bf(tile[ig * 16 + 8 + m][jl]);
    }
    u16* dst = out + (long)b * IJ + (long)(j0 + jl) * I + i0 + ig * 16;
    *(short8*)dst = o0;
    *(short8*)(dst + 8) = o1;
}

// ---------------------------------------------------------------------------
// Causal flash attention. Q,K: [B][S][D] bf16 (head-major inside D);
// VT: [B][D][S] bf16. One wave = 32 q-rows of one (b,h). No block barriers
// (waves have divergent trip counts); P round-trips through wave-private LDS.
// ---------------------------------------------------------------------------
__global__ __launch_bounds__(256) void flash_attn(
    const u16* __restrict__ Qg, const u16* __restrict__ Kg,
    const u16* __restrict__ Vt, u16* __restrict__ Og)
{
    __shared__ __align__(16) u16 plds[4][1024];   // [wave][32 rows * 32 cols]
    const int tid = threadIdx.x;
    const int wv = tid >> 6, lane = tid & 63;
    const int quad = lane >> 4, l15 = lane & 15;
    const int gw = blockIdx.x * 4 + wv;
    const int qt = gw & 31, hh = (gw >> 5) & 15, bb = gw >> 9;
    const int q0 = qt * 32;
    const long SD = 1024L * 1024L;
    const u16* Qb = Qg + (long)bb * SD + hh * 64;
    const u16* Kb = Kg + (long)bb * SD + hh * 64;
    const u16* Vb = Vt + (long)bb * SD + (long)hh * 64 * 1024;

    short8 qf[2][2];
#pragma unroll
    for (int mt = 0; mt < 2; mt++)
#pragma unroll
        for (int kb = 0; kb < 2; kb++)
            qf[mt][kb] = *(const short8*)(Qb + (long)(q0 + mt * 16 + l15) * 1024 + kb * 32 + quad * 8);

    f32x4 o[2][4];
    float mrow[2][4], lrow[2][4], alpha[2][4];
#pragma unroll
    for (int mt = 0; mt < 2; mt++) {
#pragma unroll
        for (int nt = 0; nt < 4; nt++) o[mt][nt] = (f32x4){0.f, 0.f, 0.f, 0.f};
#pragma unroll
        for (int r = 0; r < 4; r++) { mrow[mt][r] = -1e30f; lrow[mt][r] = 0.f; }
    }
    const float sc = 0.125f * 1.4426950408889634f;   // fold log2e -> exp2 domain
    u16* myp = plds[wv];

    for (int k2 = 0; k2 < q0 + 32; k2 += 32) {
        f32x4 sco[2][2];
#pragma unroll
        for (int nt = 0; nt < 2; nt++) {
            const u16* kr = Kb + (long)(k2 + nt * 16 + l15) * 1024 + quad * 8;
            short8 kf0 = *(const short8*)kr;
            short8 kf1 = *(const short8*)(kr + 32);
#pragma unroll
            for (int mt = 0; mt < 2; mt++) {
                f32x4 z = (f32x4){0.f, 0.f, 0.f, 0.f};
                z = __builtin_amdgcn_mfma_f32_16x16x32_bf16(qf[mt][0], kf0, z, 0, 0, 0);
                z = __builtin_amdgcn_mfma_f32_16x16x32_bf16(qf[mt][1], kf1, z, 0, 0, 0);
                sco[mt][nt] = z;
            }
        }
#pragma unroll
        for (int mt = 0; mt < 2; mt++) {
            const int rowb = q0 + mt * 16 + quad * 4;
#pragma unroll
            for (int r = 0; r < 4; r++) {
                float v0 = sco[mt][0][r] * sc;
                float v1 = sco[mt][1][r] * sc;
                if (k2 + l15 > rowb + r)      v0 = -1e30f;
                if (k2 + 16 + l15 > rowb + r) v1 = -1e30f;
                float cm = fmaxf(v0, v1);
                cm = fmaxf(cm, __shfl_xor(cm, 1));
                cm = fmaxf(cm, __shfl_xor(cm, 2));
                cm = fmaxf(cm, __shfl_xor(cm, 4));
                cm = fmaxf(cm, __shfl_xor(cm, 8));
                const float mn = fmaxf(mrow[mt][r], cm);
                const float a = exp2f(mrow[mt][r] - mn);
                const float p0 = exp2f(v0 - mn);
                const float p1 = exp2f(v1 - mn);
                mrow[mt][r] = mn;
                float rs = p0 + p1;
                rs += __shfl_xor(rs, 1);
                rs += __shfl_xor(rs, 2);
                rs += __shfl_xor(rs, 4);
                rs += __shfl_xor(rs, 8);
                lrow[mt][r] = lrow[mt][r] * a + rs;
                alpha[mt][r] = a;
                const int prow = mt * 16 + quad * 4 + r;
                myp[prow * 32 + l15]      = f2bf(p0);
                myp[prow * 32 + 16 + l15] = f2bf(p1);
            }
        }
        asm volatile("s_waitcnt lgkmcnt(0)" ::: "memory");
        short8 pf0 = *(const short8*)&myp[(0 + l15) * 32 + quad * 8];
        short8 pf1 = *(const short8*)&myp[(16 + l15) * 32 + quad * 8];
#pragma unroll
        for (int nt = 0; nt < 4; nt++) {
            short8 vf = *(const short8*)(Vb + (long)(nt * 16 + l15) * 1024 + k2 + quad * 8);
            f32x4 t0 = o[0][nt], t1 = o[1][nt];
#pragma unroll
            for (int r = 0; r < 4; r++) { t0[r] *= alpha[0][r]; t1[r] *= alpha[1][r]; }
            o[0][nt] = __builtin_amdgcn_mfma_f32_16x16x32_bf16(pf0, vf, t0, 0, 0, 0);
            o[1][nt] = __builtin_amdgcn_mfma_f32_16x16x32_bf16(pf1, vf, t1, 0, 0, 0);
        }
    }
#pragma unroll
    for (int mt = 0; mt < 2; mt++)
#pragma unroll
        for (int nt = 0; nt < 4; nt++)
#pragma unroll
            for (int r = 0; r < 4; r++) {
                const long row = q0 + mt * 16 + quad * 4 + r;
                const long col = hh * 64 + nt * 16 + l15;
                Og[(long)bb * SD + row * 1024 + col] = f2bf(o[mt][nt][r] / lrow[mt][r]);
            }
}

// ---------------------------------------------------------------------------
extern "C" void kernel_launch(void* const* d_in, const int* in_sizes, int n_in,
                              void* d_out, int out_size, void* d_ws, size_t ws_size,
                              hipStream_t stream)
{
    const float* x   = (const float*)d_in[0];
    const float* imp = (const float*)d_in[1];
    const float* Wr[4] = { (const float*)d_in[2], (const float*)d_in[3],
                           (const float*)d_in[4], (const float*)d_in[5] };
    const float* cn  = (const float*)d_in[6];
    const float* ep  = (const float*)d_in[7];
    const float* Wo  = (const float*)d_in[8];
    float* outp = (float*)d_out;
    char* ws = (char*)d_ws;

    // d_out (33.55 MB) doubles as scratch for x_hi/x_lo until the final GEMM.
    u16* xh = (u16*)d_out;                    // [8192][1024] bf16
    u16* xl = xh + 8388608;                   // [8192][1024] bf16

    u16*   Wh     = (u16*)(ws + 0);           // [256][1024] bf16
    u16*   Wl     = (u16*)(ws + 524288);      // [256][1024] bf16
    u16*   Wobf   = (u16*)(ws + 1048576);     // [1024][1024] bf16
    float* w_raw  = (float*)(ws + 3145728);   // [4][8][64]
    float* topw   = (float*)(ws + 3153920);   // [4][8][16]
    int*   topi   = (int*)(ws + 3155968);     // [4][8][16]
    // region reused as Kb after its tenants die:
    float* logits = (float*)(ws + 4194304);   // [8192][256] fp32 (dead after router_agg)
    u16*   scT    = (u16*)(ws + 12582912);    // [8][256][1024] (dead after h GEMM)
    u16*   eQT    = (u16*)(ws + 16777216);    // [8][1024][256] (dead after Q GEMM)
    u16*   Kb     = (u16*)(ws + 4194304);     // [8][1024][1024] (written after all above die)
    u16*   hbuf   = (u16*)(ws + 20971520);    // [8][1024][256]
    u16*   eKT    = (u16*)(ws + 25165824);    // [8][1024][256]
    u16*   eVT    = (u16*)(ws + 29360128);    // [8][1024][256]
    u16*   Qb     = (u16*)(ws + 33554432);    // [8][1024][1024]
    u16*   VTb    = (u16*)(ws + 50331648);    // [8][1024(D)][1024(S)]
    u16*   aout   = (u16*)(ws + 67108864);    // [8][1024][1024]   (total ws: 80 MB)

    // 0) precision splits / conversions
    cvt_split<<<dim3(8192), 256, 0, stream>>>(x, xh, xl, 2097152);
    for (int r = 0; r < 4; r++)
        cvt_split<<<dim3(64), 256, 0, stream>>>(Wr[r], Wh + r * 65536, Wl + r * 65536, 16384);
    cvt_bf<<<dim3(1024), 256, 0, stream>>>(Wo, Wobf, 262144);
    hipMemsetAsync(w_raw, 0, 4 * 8 * 64 * 4, stream);

    // 1) router logits in split-bf16 (3 passes, fp32 accum): err ~2^-17
    gemm_bt<float><<<dim3(64, 2, 1), 256, 0, stream>>>(
        xh, 1024, 0, Wh, 1024, 0, logits, 256, 0, 1024, 0);
    gemm_bt<float><<<dim3(64, 2, 1), 256, 0, stream>>>(
        xl, 1024, 0, Wh, 1024, 0, logits, 256, 0, 1024, 1);
    gemm_bt<float><<<dim3(64, 2, 1), 256, 0, stream>>>(
        xh, 1024, 0, Wl, 1024, 0, logits, 256, 0, 1024, 1);
    // 2) softmax + importance aggregation, 3) top-k (all fp32)
    router_agg<<<dim3(256), 128, 0, stream>>>(logits, imp, w_raw);
    topk_kernel<<<dim3(32), 64, 0, stream>>>(w_raw, topw, topi);
    // 4) gathered expert mixes (fp32 pools -> bf16, stored transposed/K-contig)
    gather_mix<<<dim3(16, 4, 8), 256, 0, stream>>>(cn, topw + 0 * 128, topi + 0 * 128, scT, 1024, 256, 16);
    gather_mix<<<dim3(4, 16, 8), 256, 0, stream>>>(ep, topw + 1 * 128, topi + 1 * 128, eQT, 256, 1024, 8);
    gather_mix<<<dim3(4, 16, 8), 256, 0, stream>>>(ep, topw + 2 * 128, topi + 2 * 128, eKT, 256, 1024, 8);
    gather_mix<<<dim3(4, 16, 8), 256, 0, stream>>>(ep, topw + 3 * 128, topi + 3 * 128, eVT, 256, 1024, 8);
    // 5) h[b] = x[b] @ scT[b]^T   (M=1024,N=256,K=1024)
    gemm_bt<u16><<<dim3(8, 2, 8), 256, 0, stream>>>(
        xh, 1024, 1048576, scT, 1024, 262144, hbuf, 256, 262144, 1024, 0);
    // 6) Q/K[b] = h[b] @ eT[b]^T  (M=1024,N=1024,K=256); K GEMM reuses dead region
    gemm_bt<u16><<<dim3(8, 8, 8), 256, 0, stream>>>(
        hbuf, 256, 262144, eQT, 256, 262144, Qb, 1024, 1048576, 256, 0);
    gemm_bt<u16><<<dim3(8, 8, 8), 256, 0, stream>>>(
        hbuf, 256, 262144, eKT, 256, 262144, Kb, 1024, 1048576, 256, 0);
    // 7) V^T[b] = eVT[b] @ h[b]^T  (M=1024(D),N=1024(S),K=256)
    gemm_bt<u16><<<dim3(8, 8, 8), 256, 0, stream>>>(
        eVT, 256, 262144, hbuf, 256, 262144, VTb, 1024, 1048576, 256, 0);
    // 8) causal flash attention
    flash_attn<<<dim3(1024), 256, 0, stream>>>(Qb, Kb, VTb, aout);
    // 9) output projection: out = aout @ W_O^T (fp32 out, overwrites xh/xl scratch)
    gemm_bt<float><<<dim3(64, 8, 1), 256, 0, stream>>>(
        aout, 1024, 0, Wobf, 1024, 0, outp, 1024, 0, 1024, 0);
}

// Round 3
// 448.804 us; speedup vs baseline: 1.3820x; 1.3820x over previous
//
#include <hip/hip_runtime.h>

typedef __attribute__((ext_vector_type(8))) short short8;
typedef __attribute__((ext_vector_type(4))) short short4v;
typedef __attribute__((ext_vector_type(4))) float f32x4;
typedef unsigned short u16;
typedef unsigned int u32;

__device__ __forceinline__ float bf2f(u16 h) {
    return __uint_as_float(((u32)h) << 16);
}
__device__ __forceinline__ u16 f2bf(float f) {
    u32 u = __float_as_uint(f);
    u32 r = u + 0x7fffu + ((u >> 16) & 1u);   // RNE
    return (u16)(r >> 16);
}
// pack hi16(a), hi16(b) -> (b.hi<<16)|a.hi  (truncating bf16 pack, 1 instr)
__device__ __forceinline__ u32 pack_bf(float a, float b) {
    return __builtin_amdgcn_perm(__float_as_uint(b), __float_as_uint(a), 0x07060302u);
}

__device__ __forceinline__ void async_copy16(const void* g, void* l) {
    __builtin_amdgcn_global_load_lds(
        (const __attribute__((address_space(1))) void*)g,
        (__attribute__((address_space(3))) void*)l, 16, 0, 0);
}

// ---------------------------------------------------------------------------
// fp32 -> (bf16 hi, bf16 lo) split conversion. lo = bf16(v - f(hi)).
// ---------------------------------------------------------------------------
__global__ __launch_bounds__(256) void cvt_split(
    const float* __restrict__ in, u16* __restrict__ hi, u16* __restrict__ lo, int n4)
{
    int i = blockIdx.x * 256 + threadIdx.x;
    if (i >= n4) return;
    float4 v = ((const float4*)in)[i];
    short4v h, l;
    float vv[4] = {v.x, v.y, v.z, v.w};
#pragma unroll
    for (int j = 0; j < 4; j++) {
        u16 hb = f2bf(vv[j]);
        h[j] = (short)hb;
        l[j] = (short)f2bf(vv[j] - bf2f(hb));
    }
    ((short4v*)hi)[i] = h;
    ((short4v*)lo)[i] = l;
}

// 4 router weight matrices in one launch: 64 blocks per router.
__global__ __launch_bounds__(256) void cvt_split_w4(
    const float* __restrict__ w0, const float* __restrict__ w1,
    const float* __restrict__ w2, const float* __restrict__ w3,
    u16* __restrict__ hi, u16* __restrict__ lo)
{
    const int r = blockIdx.x >> 6;
    const float* src = (r == 0) ? w0 : (r == 1) ? w1 : (r == 2) ? w2 : w3;
    int i = (blockIdx.x & 63) * 256 + threadIdx.x;   // < 16384 float4s
    float4 v = ((const float4*)src)[i];
    short4v h, l;
    float vv[4] = {v.x, v.y, v.z, v.w};
#pragma unroll
    for (int j = 0; j < 4; j++) {
        u16 hb = f2bf(vv[j]);
        h[j] = (short)hb;
        l[j] = (short)f2bf(vv[j] - bf2f(hb));
    }
    ((short4v*)(hi + (long)r * 65536))[i] = h;
    ((short4v*)(lo + (long)r * 65536))[i] = l;
}

__global__ __launch_bounds__(256) void cvt_bf(
    const float* __restrict__ in, u16* __restrict__ out, int n4)
{
    int i = blockIdx.x * 256 + threadIdx.x;
    if (i >= n4) return;
    float4 v = ((const float4*)in)[i];
    short4v h;
    h[0] = (short)f2bf(v.x); h[1] = (short)f2bf(v.y);
    h[2] = (short)f2bf(v.z); h[3] = (short)f2bf(v.w);
    ((short4v*)out)[i] = h;
}

// ---------------------------------------------------------------------------
// bf16 GEMM: C[M][N] = cscale * (A[M][K] * B[N][K]^T). m97 structure.
// ---------------------------------------------------------------------------
template <typename CT>
__global__ __launch_bounds__(256) void gemm_bt(
    const u16* __restrict__ A, long lda, long bsA,
    const u16* __restrict__ Bm, long ldb, long bsB,
    CT* __restrict__ C, long ldc, long bsC, int K, float cscale)
{
    __shared__ __align__(16) u16 lsA[128 * 32];
    __shared__ __align__(16) u16 lsB[128 * 32];
    const int tid = threadIdx.x;
    const int wave = tid >> 6, lane = tid & 63;
    const int quad = lane >> 4, l15 = lane & 15;
    const int wm = wave >> 1, wn = wave & 1;
    const long m0 = (long)blockIdx.x * 128, n0 = (long)blockIdx.y * 128;
    A  += (long)blockIdx.z * bsA;
    Bm += (long)blockIdx.z * bsB;
    C  += (long)blockIdx.z * bsC;
    const int srow = lane >> 2, scol = (lane & 3) * 8;

    f32x4 acc[4][4];
#pragma unroll
    for (int i = 0; i < 4; i++)
#pragma unroll
        for (int j = 0; j < 4; j++) acc[i][j] = (f32x4){0.f, 0.f, 0.f, 0.f};

    const u16* ga0 = A + (m0 + (wave * 2 + 0) * 16 + srow) * lda + scol;
    const u16* ga1 = A + (m0 + (wave * 2 + 1) * 16 + srow) * lda + scol;
    const u16* gb0 = Bm + (n0 + (wave * 2 + 0) * 16 + srow) * ldb + scol;
    const u16* gb1 = Bm + (n0 + (wave * 2 + 1) * 16 + srow) * ldb + scol;
    u16* la0 = &lsA[(wave * 2 + 0) * 512];
    u16* la1 = &lsA[(wave * 2 + 1) * 512];
    u16* lb0 = &lsB[(wave * 2 + 0) * 512];
    u16* lb1 = &lsB[(wave * 2 + 1) * 512];

    for (int kk = 0; kk < K; kk += 32) {
        async_copy16(ga0 + kk, la0);
        async_copy16(ga1 + kk, la1);
        async_copy16(gb0 + kk, lb0);
        async_copy16(gb1 + kk, lb1);
        __syncthreads();
        short8 af[4], bf[4];
#pragma unroll
        for (int mt = 0; mt < 4; mt++)
            af[mt] = *(const short8*)&lsA[(wm * 64 + mt * 16 + l15) * 32 + quad * 8];
#pragma unroll
        for (int nt = 0; nt < 4; nt++)
            bf[nt] = *(const short8*)&lsB[(wn * 64 + nt * 16 + l15) * 32 + quad * 8];
#pragma unroll
        for (int mt = 0; mt < 4; mt++)
#pragma unroll
            for (int nt = 0; nt < 4; nt++)
                acc[mt][nt] = __builtin_amdgcn_mfma_f32_16x16x32_bf16(
                    af[mt], bf[nt], acc[mt][nt], 0, 0, 0);
        __syncthreads();
    }
#pragma unroll
    for (int mt = 0; mt < 4; mt++) {
        const long rowb = m0 + wm * 64 + mt * 16 + quad * 4;
#pragma unroll
        for (int nt = 0; nt < 4; nt++) {
            const long col = n0 + wn * 64 + nt * 16 + l15;
#pragma unroll
            for (int r = 0; r < 4; r++) {
                const float v = acc[mt][nt][r] * cscale;
                if constexpr (sizeof(CT) == 2)
                    C[(rowb + r) * ldc + col] = f2bf(v);
                else
                    C[(rowb + r) * ldc + col] = v;
            }
        }
    }
}

// ---------------------------------------------------------------------------
// Fused split-bf16 router logits: C = Ah*Bh^T + Al*Bh^T + Ah*Bl^T (fp32 C).
// M=8192, N=256, K=1024, lda=ldb=1024. Grid (64,2).
// ---------------------------------------------------------------------------
__global__ __launch_bounds__(256) void gemm_router(
    const u16* __restrict__ Ah, const u16* __restrict__ Al,
    const u16* __restrict__ Bh, const u16* __restrict__ Bl,
    float* __restrict__ C)
{
    __shared__ __align__(16) u16 lsA[128 * 32];
    __shared__ __align__(16) u16 lsB[128 * 32];
    const int tid = threadIdx.x;
    const int wave = tid >> 6, lane = tid & 63;
    const int quad = lane >> 4, l15 = lane & 15;
    const int wm = wave >> 1, wn = wave & 1;
    const long m0 = (long)blockIdx.x * 128, n0 = (long)blockIdx.y * 128;
    const int srow = lane >> 2, scol = (lane & 3) * 8;
    const long offA = (m0 + (wave * 2) * 16 + srow) * 1024 + scol;
    const long offB = (n0 + (wave * 2) * 16 + srow) * 1024 + scol;
    u16* la0 = &lsA[(wave * 2 + 0) * 512];
    u16* la1 = &lsA[(wave * 2 + 1) * 512];
    u16* lb0 = &lsB[(wave * 2 + 0) * 512];
    u16* lb1 = &lsB[(wave * 2 + 1) * 512];

    f32x4 acc[4][4];
#pragma unroll
    for (int i = 0; i < 4; i++)
#pragma unroll
        for (int j = 0; j < 4; j++) acc[i][j] = (f32x4){0.f, 0.f, 0.f, 0.f};

    for (int seg = 0; seg < 3; seg++) {
        const u16* A = (seg == 1) ? Al : Ah;
        const u16* B = (seg == 2) ? Bl : Bh;
        const u16* ga = A + offA;
        const u16* gb = B + offB;
        for (int kk = 0; kk < 1024; kk += 32) {
            async_copy16(ga + kk, la0);
            async_copy16(ga + 16384 + kk, la1);
            async_copy16(gb + kk, lb0);
            async_copy16(gb + 16384 + kk, lb1);
            __syncthreads();
            short8 af[4], bf[4];
#pragma unroll
            for (int mt = 0; mt < 4; mt++)
                af[mt] = *(const short8*)&lsA[(wm * 64 + mt * 16 + l15) * 32 + quad * 8];
#pragma unroll
            for (int nt = 0; nt < 4; nt++)
                bf[nt] = *(const short8*)&lsB[(wn * 64 + nt * 16 + l15) * 32 + quad * 8];
#pragma unroll
            for (int mt = 0; mt < 4; mt++)
#pragma unroll
                for (int nt = 0; nt < 4; nt++)
                    acc[mt][nt] = __builtin_amdgcn_mfma_f32_16x16x32_bf16(
                        af[mt], bf[nt], acc[mt][nt], 0, 0, 0);
            __syncthreads();
        }
    }
#pragma unroll
    for (int mt = 0; mt < 4; mt++) {
        const long rowb = m0 + wm * 64 + mt * 16 + quad * 4;
#pragma unroll
        for (int nt = 0; nt < 4; nt++) {
            const long col = n0 + wn * 64 + nt * 16 + l15;
#pragma unroll
            for (int r = 0; r < 4; r++)
                C[(rowb + r) * 256 + col] = acc[mt][nt][r];
        }
    }
}

// ---------------------------------------------------------------------------
// Per-token softmax over each router's 64 logits, scaled by importance,
// summed over tokens into w_raw[4][8][64] (fp32 atomics).
// ---------------------------------------------------------------------------
__global__ __launch_bounds__(128) void router_agg(
    const float* __restrict__ logits, const float* __restrict__ imp,
    float* __restrict__ w_raw)
{
    __shared__ float pref[32][257];
    const int tid = threadIdx.x;
    const int tl = tid >> 2, r = tid & 3;
    const int s = blockIdx.x * 32 + tl;
    const int b = s >> 10;
    const float* lp = logits + (long)s * 256 + r * 64;
    float v[64];
#pragma unroll
    for (int i = 0; i < 16; i++) {
        float4 f = ((const float4*)lp)[i];
        v[i * 4 + 0] = f.x; v[i * 4 + 1] = f.y;
        v[i * 4 + 2] = f.z; v[i * 4 + 3] = f.w;
    }
    float mx = v[0];
#pragma unroll
    for (int i = 1; i < 64; i++) mx = fmaxf(mx, v[i]);
    float sum = 0.f;
#pragma unroll
    for (int i = 0; i < 64; i++) { v[i] = __expf(v[i] - mx); sum += v[i]; }
    const float scale = imp[s] / sum;
#pragma unroll
    for (int i = 0; i < 64; i++) pref[tl][r * 64 + i] = v[i] * scale;
    __syncthreads();
#pragma unroll
    for (int half = 0; half < 2; half++) {
        const int idx = tid + half * 128;
        const int r2 = idx >> 6, n = idx & 63;
        float acc = 0.f;
#pragma unroll 8
        for (int t = 0; t < 32; t++) acc += pref[t][r2 * 64 + n];
        atomicAdd(&w_raw[(r2 * 8 + b) * 64 + n], acc);
    }
}

// ---------------------------------------------------------------------------
// Normalize w, top-k (k=16 router 0, else 8), renormalize.
// ---------------------------------------------------------------------------
__global__ void topk_kernel(const float* __restrict__ w_raw,
                            float* __restrict__ topw, int* __restrict__ topi)
{
    const int r = blockIdx.x >> 3, b = blockIdx.x & 7;
    const int lane = threadIdx.x;
    const int k = (r == 0) ? 16 : 8;
    float w = w_raw[(r * 8 + b) * 64 + lane];
    float tot = w;
    for (int o2 = 32; o2 >= 1; o2 >>= 1) tot += __shfl_xor(tot, o2);
    w = w / (tot + 1e-8f);
    __shared__ float tw[16];
    __shared__ int ti[16];
    float cur = w;
    float ssum = 0.f;
    for (int j = 0; j < k; j++) {
        float m = cur; int mi = lane;
        for (int o2 = 32; o2 >= 1; o2 >>= 1) {
            float om = __shfl_xor(m, o2); int oi = __shfl_xor(mi, o2);
            if (om > m || (om == m && oi < mi)) { m = om; mi = oi; }
        }
        if (lane == 0) { tw[j] = m; ti[j] = mi; }
        ssum += m;
        if (lane == mi) cur = -1e30f;
    }
    __syncthreads();
    if (lane < 16) {
        topw[(r * 8 + b) * 16 + lane] = (lane < k) ? tw[lane] / (ssum + 1e-8f) : 0.f;
        topi[(r * 8 + b) * 16 + lane] = (lane < k) ? ti[lane] : 0;
    }
}

// ---------------------------------------------------------------------------
// out[b][j][i] = sum_k w[b,k] * pool[idx[b,k]][i][j]   (transposing gather-mix)
// ---------------------------------------------------------------------------
__global__ __launch_bounds__(256) void gather_mix(
    const float* __restrict__ pool, const float* __restrict__ topw,
    const int* __restrict__ topi, u16* __restrict__ out,
    int I, int J, int k)
{
    __shared__ float tile[64][65];
    const int b = blockIdx.z;
    const long IJ = (long)I * J;
    const int i0 = blockIdx.x * 64, j0 = blockIdx.y * 64;
    const float* tw = topw + b * 16;
    const int* ti = topi + b * 16;
    const int tid = threadIdx.x;
    const int il = tid >> 2, jg = tid & 3;
    float acc[16];
#pragma unroll
    for (int m = 0; m < 16; m++) acc[m] = 0.f;
    for (int kk = 0; kk < k; kk++) {
        const float wgt = tw[kk];
        const long n = ti[kk];
        const float* src = pool + n * IJ + (long)(i0 + il) * J + j0 + jg * 16;
        float4 a0 = ((const float4*)src)[0];
        float4 a1 = ((const float4*)src)[1];
        float4 a2 = ((const float4*)src)[2];
        float4 a3 = ((const float4*)src)[3];
        acc[0] += wgt * a0.x;  acc[1] += wgt * a0.y;
        acc[2] += wgt * a0.z;  acc[3] += wgt * a0.w;
        acc[4] += wgt * a1.x;  acc[5] += wgt * a1.y;
        acc[6] += wgt * a1.z;  acc[7] += wgt * a1.w;
        acc[8] += wgt * a2.x;  acc[9] += wgt * a2.y;
        acc[10] += wgt * a2.z; acc[11] += wgt * a2.w;
        acc[12] += wgt * a3.x; acc[13] += wgt * a3.y;
        acc[14] += wgt * a3.z; acc[15] += wgt * a3.w;
    }
#pragma unroll
    for (int m = 0; m < 16; m++) tile[il][jg * 16 + m] = acc[m];
    __syncthreads();
    const int jl = tid >> 2, ig = tid & 3;
    short8 o0, o1;
#pragma unroll
    for (int m = 0; m < 8; m++) {
        o0[m] = (short)f2bf(tile[ig * 16 + m][jl]);
        o1[m] = (short)f2bf(tile[ig * 16 + 8 + m][jl]);
    }
    u16* dst = out + (long)b * IJ + (long)(j0 + jl) * I + i0 + ig * 16;
    *(short8*)dst = o0;
    *(short8*)(dst + 8) = o1;
}

// ---------------------------------------------------------------------------
// Causal flash attention, S^T formulation.
// Q (pre-scaled by 1/8*log2e), K: [B][S][D] bf16; VT: [B][D][S] bf16.
// One wave = q-tiles {pr, 31-pr} of one (b,h) -> exactly 17 64-key iterations.
// S^T = K·Q^T puts q on lane&15: softmax reductions are 2 shfl_xor per q-set.
// ---------------------------------------------------------------------------
__global__ __launch_bounds__(256, 2) void flash_attn(
    const u16* __restrict__ Qg, const u16* __restrict__ Kg,
    const u16* __restrict__ Vt, u16* __restrict__ Og)
{
    __shared__ __align__(16) u16 plds[4][32 * 72];   // per-wave P, stride 72 u16
    const int tid = threadIdx.x;
    const int wv = tid >> 6, lane = tid & 63;
    const int quad = lane >> 4, l15 = lane & 15;
    const int gw = blockIdx.x * 4 + wv;
    const int pr = gw & 15;
    const int bh = gw >> 4;                  // 0..127, same for all waves in block
    const int hh = bh & 15, bb = bh >> 4;
    const long SD = 1024L * 1024L;
    const u16* Qb = Qg + (long)bb * SD + hh * 64;
    const u16* Kb = Kg + (long)bb * SD + hh * 64;
    const u16* Vb = Vt + (long)bb * SD + (long)hh * 64 * 1024;
    u16* myp = plds[wv];

    for (int half = 0; half < 2; half++) {
        const int qt = half ? (31 - pr) : pr;
        const int q0 = qt * 32;

        short8 qf[2][2];
#pragma unroll
        for (int mt = 0; mt < 2; mt++)
#pragma unroll
            for (int kb = 0; kb < 2; kb++)
                qf[mt][kb] = *(const short8*)(Qb + (long)(q0 + mt * 16 + l15) * 1024 + kb * 32 + quad * 8);

        f32x4 o[2][4];
        float mrow[2] = {-3e38f, -3e38f}, lrow[2] = {0.f, 0.f};
#pragma unroll
        for (int mt = 0; mt < 2; mt++)
#pragma unroll
            for (int nt = 0; nt < 4; nt++) o[mt][nt] = (f32x4){0.f, 0.f, 0.f, 0.f};

        const int ntile = (q0 + 95) >> 6;    // ceil((q0+32)/64)
        short8 kf[4][2], kn[4][2];
#pragma unroll
        for (int kt = 0; kt < 4; kt++)
#pragma unroll
            for (int kb = 0; kb < 2; kb++)
                kf[kt][kb] = *(const short8*)(Kb + (long)(kt * 16 + l15) * 1024 + kb * 32 + quad * 8);

        for (int it = 0; it < ntile; it++) {
            const int k2 = it * 64;
            const bool last = (it == ntile - 1);
            // S^T[key][q] = K·Q^T
            f32x4 st[4][2];
#pragma unroll
            for (int kt = 0; kt < 4; kt++)
#pragma unroll
                for (int q_ = 0; q_ < 2; q_++) {
                    f32x4 z = (f32x4){0.f, 0.f, 0.f, 0.f};
                    z = __builtin_amdgcn_mfma_f32_16x16x32_bf16(kf[kt][0], qf[q_][0], z, 0, 0, 0);
                    z = __builtin_amdgcn_mfma_f32_16x16x32_bf16(kf[kt][1], qf[q_][1], z, 0, 0, 0);
                    st[kt][q_] = z;
                }
            // V loads for this iter (latency hidden under softmax)
            short8 vf[4][2];
#pragma unroll
            for (int nt = 0; nt < 4; nt++)
#pragma unroll
                for (int kh = 0; kh < 2; kh++)
                    vf[nt][kh] = *(const short8*)(Vb + (long)(nt * 16 + l15) * 1024 + k2 + kh * 32 + quad * 8);
            // prefetch next K tile
            if (it + 1 < ntile) {
#pragma unroll
                for (int kt = 0; kt < 4; kt++)
#pragma unroll
                    for (int kb = 0; kb < 2; kb++)
                        kn[kt][kb] = *(const short8*)(Kb + (long)(k2 + 64 + kt * 16 + l15) * 1024 + kb * 32 + quad * 8);
            }
            // online softmax per q-column (lane&15 holds q)
            float am[2];
#pragma unroll
            for (int q_ = 0; q_ < 2; q_++) {
                if (last) {
#pragma unroll
                    for (int kt = 0; kt < 4; kt++)
#pragma unroll
                        for (int r = 0; r < 4; r++)
                            if (k2 + kt * 16 + quad * 4 + r > q0 + q_ * 16 + l15)
                                st[kt][q_][r] = -3e38f;
                }
                float cm = -3e38f;
#pragma unroll
                for (int kt = 0; kt < 4; kt++)
#pragma unroll
                    for (int r = 0; r < 4; r++) cm = fmaxf(cm, st[kt][q_][r]);
                cm = fmaxf(cm, __shfl_xor(cm, 16));
                cm = fmaxf(cm, __shfl_xor(cm, 32));
                const float mn = fmaxf(mrow[q_], cm);
                am[q_] = exp2f(mrow[q_] - mn);
                mrow[q_] = mn;
                // fold +log2(1+2^-9) so the truncating bf16 pack is ~unbiased
                const float moff = 0.00281502f - mn;
                float rs = 0.f;
#pragma unroll
                for (int kt = 0; kt < 4; kt++) {
                    float p0 = exp2f(st[kt][q_][0] + moff);
                    float p1 = exp2f(st[kt][q_][1] + moff);
                    float p2 = exp2f(st[kt][q_][2] + moff);
                    float p3 = exp2f(st[kt][q_][3] + moff);
                    rs += (p0 + p1) + (p2 + p3);
                    u32 w0 = pack_bf(p0, p1);
                    u32 w1 = pack_bf(p2, p3);
                    *(uint2*)&myp[(q_ * 16 + l15) * 72 + kt * 16 + quad * 4] = make_uint2(w0, w1);
                }
                rs += __shfl_xor(rs, 16);
                rs += __shfl_xor(rs, 32);
                lrow[q_] = lrow[q_] * am[q_] + rs;
            }
            // redistribute alpha from q-on-l15 to q-on-row layout
            float av[2][4];
#pragma unroll
            for (int mt = 0; mt < 2; mt++)
#pragma unroll
                for (int r = 0; r < 4; r++)
                    av[mt][r] = __shfl(am[mt], quad * 4 + r);
            asm volatile("s_waitcnt lgkmcnt(0)" ::: "memory");
            short8 pf0[2], pf1[2];
#pragma unroll
            for (int kh = 0; kh < 2; kh++) {
                pf0[kh] = *(const short8*)&myp[(l15) * 72 + kh * 32 + quad * 8];
                pf1[kh] = *(const short8*)&myp[(16 + l15) * 72 + kh * 32 + quad * 8];
            }
#pragma unroll
            for (int mt = 0; mt < 2; mt++)
#pragma unroll
                for (int nt = 0; nt < 4; nt++)
#pragma unroll
                    for (int r = 0; r < 4; r++) o[mt][nt][r] *= av[mt][r];
#pragma unroll
            for (int nt = 0; nt < 4; nt++)
#pragma unroll
                for (int kh = 0; kh < 2; kh++) {
                    o[0][nt] = __builtin_amdgcn_mfma_f32_16x16x32_bf16(pf0[kh], vf[nt][kh], o[0][nt], 0, 0, 0);
                    o[1][nt] = __builtin_amdgcn_mfma_f32_16x16x32_bf16(pf1[kh], vf[nt][kh], o[1][nt], 0, 0, 0);
                }
            if (it + 1 < ntile) {
#pragma unroll
                for (int kt = 0; kt < 4; kt++)
#pragma unroll
                    for (int kb = 0; kb < 2; kb++) kf[kt][kb] = kn[kt][kb];
            }
        }
        // epilogue
#pragma unroll
        for (int mt = 0; mt < 2; mt++)
#pragma unroll
            for (int r = 0; r < 4; r++) {
                const float li = 1.0f / __shfl(lrow[mt], quad * 4 + r);
                const long row = q0 + mt * 16 + quad * 4 + r;
#pragma unroll
                for (int nt = 0; nt < 4; nt++)
                    Og[(long)bb * SD + row * 1024 + hh * 64 + nt * 16 + l15] =
                        f2bf(o[mt][nt][r] * li);
            }
    }
}

// ---------------------------------------------------------------------------
extern "C" void kernel_launch(void* const* d_in, const int* in_sizes, int n_in,
                              void* d_out, int out_size, void* d_ws, size_t ws_size,
                              hipStream_t stream)
{
    const float* x   = (const float*)d_in[0];
    const float* imp = (const float*)d_in[1];
    const float* cn  = (const float*)d_in[6];
    const float* ep  = (const float*)d_in[7];
    const float* Wo  = (const float*)d_in[8];
    float* outp = (float*)d_out;
    char* ws = (char*)d_ws;

    // d_out (33.55 MB) doubles as scratch for x_hi/x_lo until the final GEMM.
    u16* xh = (u16*)d_out;                    // [8192][1024] bf16
    u16* xl = xh + 8388608;                   // [8192][1024] bf16

    u16*   Wh     = (u16*)(ws + 0);           // [256][1024] bf16
    u16*   Wl     = (u16*)(ws + 524288);      // [256][1024] bf16
    u16*   Wobf   = (u16*)(ws + 1048576);     // [1024][1024] bf16
    float* w_raw  = (float*)(ws + 3145728);   // [4][8][64]
    float* topw   = (float*)(ws + 3153920);   // [4][8][16]
    int*   topi   = (int*)(ws + 3155968);     // [4][8][16]
    // region reused as Kb after its tenants die:
    float* logits = (float*)(ws + 4194304);   // [8192][256] fp32 (dead after router_agg)
    u16*   scT    = (u16*)(ws + 12582912);    // [8][256][1024] (dead after h GEMM)
    u16*   eQT    = (u16*)(ws + 16777216);    // [8][1024][256] (dead after Q GEMM)
    u16*   Kb     = (u16*)(ws + 4194304);     // [8][1024][1024] (written after all above die)
    u16*   hbuf   = (u16*)(ws + 20971520);    // [8][1024][256]
    u16*   eKT    = (u16*)(ws + 25165824);    // [8][1024][256]
    u16*   eVT    = (u16*)(ws + 29360128);    // [8][1024][256]
    u16*   Qb     = (u16*)(ws + 33554432);    // [8][1024][1024]
    u16*   VTb    = (u16*)(ws + 50331648);    // [8][1024(D)][1024(S)]
    u16*   aout   = (u16*)(ws + 67108864);    // [8][1024][1024]

    // 0) precision splits / conversions
    cvt_split<<<dim3(8192), 256, 0, stream>>>(x, xh, xl, 2097152);
    cvt_split_w4<<<dim3(256), 256, 0, stream>>>(
        (const float*)d_in[2], (const float*)d_in[3],
        (const float*)d_in[4], (const float*)d_in[5], Wh, Wl);
    cvt_bf<<<dim3(1024), 256, 0, stream>>>(Wo, Wobf, 262144);
    hipMemsetAsync(w_raw, 0, 4 * 8 * 64 * 4, stream);

    // 1) router logits, fused split-bf16 (err ~2^-17)
    gemm_router<<<dim3(64, 2, 1), 256, 0, stream>>>(xh, xl, Wh, Wl, logits);
    // 2) softmax + importance aggregation, 3) top-k (all fp32)
    router_agg<<<dim3(256), 128, 0, stream>>>(logits, imp, w_raw);
    topk_kernel<<<dim3(32), 64, 0, stream>>>(w_raw, topw, topi);
    // 4) gathered expert mixes (fp32 pools -> bf16, stored transposed/K-contig)
    gather_mix<<<dim3(16, 4, 8), 256, 0, stream>>>(cn, topw + 0 * 128, topi + 0 * 128, scT, 1024, 256, 16);
    gather_mix<<<dim3(4, 16, 8), 256, 0, stream>>>(ep, topw + 1 * 128, topi + 1 * 128, eQT, 256, 1024, 8);
    gather_mix<<<dim3(4, 16, 8), 256, 0, stream>>>(ep, topw + 2 * 128, topi + 2 * 128, eKT, 256, 1024, 8);
    gather_mix<<<dim3(4, 16, 8), 256, 0, stream>>>(ep, topw + 3 * 128, topi + 3 * 128, eVT, 256, 1024, 8);
    // 5) h[b] = x[b] @ scT[b]^T   (M=1024,N=256,K=1024)
    gemm_bt<u16><<<dim3(8, 2, 8), 256, 0, stream>>>(
        xh, 1024, 1048576, scT, 1024, 262144, hbuf, 256, 262144, 1024, 1.0f);
    // 6) Q/K[b] = h[b] @ eT[b]^T  (M=1024,N=1024,K=256)
    //    Q gets 1/sqrt(64)*log2(e) folded in for the exp2-domain flash kernel.
    gemm_bt<u16><<<dim3(8, 8, 8), 256, 0, stream>>>(
        hbuf, 256, 262144, eQT, 256, 262144, Qb, 1024, 1048576, 256, 0.180336880111f);
    gemm_bt<u16><<<dim3(8, 8, 8), 256, 0, stream>>>(
        hbuf, 256, 262144, eKT, 256, 262144, Kb, 1024, 1048576, 256, 1.0f);
    // 7) V^T[b] = eVT[b] @ h[b]^T  (M=1024(D),N=1024(S),K=256)
    gemm_bt<u16><<<dim3(8, 8, 8), 256, 0, stream>>>(
        eVT, 256, 262144, hbuf, 256, 262144, VTb, 1024, 1048576, 256, 1.0f);
    // 8) causal flash attention (512 blocks = 2/CU, perfectly balanced pairs)
    flash_attn<<<dim3(512), 256, 0, stream>>>(Qb, Kb, VTb, aout);
    // 9) output projection: out = aout @ W_O^T (fp32 out, overwrites xh/xl scratch)
    gemm_bt<float><<<dim3(64, 8, 1), 256, 0, stream>>>(
        aout, 1024, 0, Wobf, 1024, 0, outp, 1024, 0, 1024, 1.0f);
}